// Round 4
// baseline (420.700 us; speedup 1.0000x reference)
//
#include <hip/hip_runtime.h>

// PNN round 9: stream-select (dense reads replace sparse gather).
//
// Evidence chain:
//   r6: removing 42 MB of staging traffic changed dur by 1.6 us -> gather is
//       latency-bound, BW idle.
//   r8: windowed-random gather (128 KB windows) was NO faster than full-
//       random -> locality (TLB/DRAM-row) is not the constraint; sparse-miss
//       throughput is. Only ~16% of each window's lines were touched.
// Conclusion: make the table reads DENSE. Streaming the whole 249.6 MB table
// coalesced costs ~40 us at 6.3 TB/s -- cheaper than ~130 us of sparse
// gathering.
//
//   K0 pnn_zero:   zero 3822 bucket cursors (64 B-strided).
//   K1 pnn_bin:    bucket = f*98 + (idx>>10); atomicAdd cursor; append
//                  {b | idx_local<<14, xv}. lambda=168, CAP=320 (~11 sigma).
//   K2 pnn_select: one block per bucket. Stream the ENTIRE 64 KB table
//                  window into LDS (coalesced dwordx4 -- union of windows =
//                  table, each line read exactly once). Then each entry
//                  reads its row from LDS, scales by xv, writes one full
//                  64 B line to Aemb[b][f][16] fp32 coalesced.
//   K3 pnn_gemm:   round-8 verified GEMM+MLP reading Aemb coalesced.
//
// Bytes: 250 stream + 42 write + 42 read + ~12 misc = ~346 MB -> ~55 us
// floor. Prediction: chain ~150 -> 70-85 us; dur 318 -> ~245-265.

namespace {

typedef _Float16 half8 __attribute__((ext_vector_type(8)));
typedef _Float16 half4 __attribute__((ext_vector_type(4)));
typedef float floatx4 __attribute__((ext_vector_type(4)));
typedef float f32x4 __attribute__((ext_vector_type(4)));

constexpr int Bn = 16384;
constexpr int Fn = 39;
constexpr int Vn = 100000;
constexpr int En = 16;
constexpr int M = 32;                 // rows per gemm block
constexpr int KST = 20;               // k-steps of 32 (624 padded to 640)
constexpr int GITER = 10;             // ceil(4992 / 512) staging chunk-iters
constexpr int NTOT = Bn * Fn;         // 638,976 entries

// ---- binning geometry ----
constexpr int CHUNK_LOG = 10;                     // 1024 vocab rows / window
constexpr int CHUNK = 1 << CHUNK_LOG;             // 64 KB table window
constexpr int NB = (Vn + CHUNK - 1) / CHUNK;      // 98
constexpr int NBUCKET = Fn * NB;                  // 3822
constexpr int CAP = 320;                          // lambda=168 -> ~11 sigma
constexpr int CUR_STRIDE = 16;                    // one cursor per 64 B line

// ---- workspace layout (bytes) ----
constexpr size_t OFF_CUR = 0;                     // 3822 * 64 = 244,608
constexpr size_t OFF_ENT = 262144;                // 3822*320*8 = 9,784,320
constexpr size_t OFF_AEMB = 16777216;             // 16384*39*16*4 = 40,894,464

__device__ __forceinline__ half8 cvt8(float4 a, float4 b) {
    half8 h;
    h[0] = (_Float16)a.x; h[1] = (_Float16)a.y;
    h[2] = (_Float16)a.z; h[3] = (_Float16)a.w;
    h[4] = (_Float16)b.x; h[5] = (_Float16)b.y;
    h[6] = (_Float16)b.z; h[7] = (_Float16)b.w;
    return h;
}

__device__ __forceinline__ half4 cvt4(f32x4 a) {
    half4 h;
    h[0] = (_Float16)a[0];
    h[1] = (_Float16)a[1];
    h[2] = (_Float16)a[2];
    h[3] = (_Float16)a[3];
    return h;
}

// ---------------- K0: zero bucket cursors ----------------
__global__ __launch_bounds__(256) void pnn_zero(unsigned int* __restrict__ cur)
{
    const int i = blockIdx.x * 256 + threadIdx.x;
    if (i < NBUCKET) cur[(size_t)i * CUR_STRIDE] = 0u;
}

// ---------------- K1: bin entries by (feature, idx window) ----------------
__global__ __launch_bounds__(256) void pnn_bin(
    const int* __restrict__ Xi,
    const float* __restrict__ Xv,
    unsigned int* __restrict__ cur,
    uint2* __restrict__ ent)
{
    const int i = blockIdx.x * 256 + threadIdx.x;
    if (i >= NTOT) return;
    const unsigned int idx = (unsigned int)Xi[i];
    const float v = Xv[i];
    const unsigned int b = (unsigned int)i / (unsigned int)Fn;
    const unsigned int f = (unsigned int)i - b * (unsigned int)Fn;
    const unsigned int bucket = f * NB + (idx >> CHUNK_LOG);
    const unsigned int pos = atomicAdd(&cur[(size_t)bucket * CUR_STRIDE], 1u);
    if (pos < CAP) {
        uint2 e;
        e.x = b | ((idx & (unsigned int)(CHUNK - 1)) << 14);  // b:14b, il:10b
        e.y = __float_as_uint(v);
        ent[(size_t)bucket * CAP + pos] = e;
    }
}

// ---------------- K2: stream window -> LDS -> scaled fp32 Aemb ----------------
__global__ __launch_bounds__(512) void pnn_select(
    const float* __restrict__ T,
    const unsigned int* __restrict__ cur,
    const uint2* __restrict__ ent,
    float* __restrict__ Aemb)
{
    __shared__ float Lw[CHUNK * En];          // 65,536 B window
    const int blk = blockIdx.x;               // 0..3821
    const int f = blk / NB;
    const int ch = blk - f * NB;
    const int tid = threadIdx.x;

    // dense coalesced stream of the whole window (each table line read
    // exactly once across the grid)
    const int rows = min(CHUNK, Vn - ch * CHUNK);   // 1024, last window 672
    const f32x4* __restrict__ T4 = reinterpret_cast<const f32x4*>(
        T + ((size_t)f * Vn + (size_t)ch * CHUNK) * En);
    f32x4* L4 = reinterpret_cast<f32x4*>(Lw);
    const int nchunk = rows * 4;              // 16 B chunks
    for (int i = tid; i < nchunk; i += 512)
        L4[i] = T4[i];
    __syncthreads();

    // selection: 4 lanes per entry; LDS random read, HBM coalesced write
    unsigned int cnt = cur[(size_t)blk * CUR_STRIDE];
    if (cnt > CAP) cnt = CAP;
    const int ntask = (int)cnt * 4;
    const uint2* __restrict__ eb = ent + (size_t)blk * CAP;
    for (int task = tid; task < ntask; task += 512) {
        const uint2 e = eb[task >> 2];
        const int c = task & 3;
        const unsigned int b = e.x & 16383u;
        const unsigned int il = e.x >> 14;
        const float s = __uint_as_float(e.y);
        const f32x4 v = L4[il * 4 + c];
        f32x4 r;
        r[0] = v[0] * s;
        r[1] = v[1] * s;
        r[2] = v[2] * s;
        r[3] = v[3] * s;
        *reinterpret_cast<f32x4*>(
            Aemb + ((size_t)b * Fn + f) * En + c * 4) = r;
    }
}

// ---------------- K3: GEMM + fused MLP (verified) ----------------
struct SMemGather {
    _Float16 At[2][KST * 512];   // 2 rowtiles x 10240 halfs = 40 KB
};
struct SMemMlp {
    float x[M * 69];
    float wsh[2176];
    float r1[1024];
    float r2[1024];
};
union SMemU {
    SMemGather g;
    SMemMlp m;
};

__global__ __launch_bounds__(512, 4) void pnn_gemm(
    const float* __restrict__ Aemb,
    const float* __restrict__ w_first,
    const float* __restrict__ w_inner,
    const float* __restrict__ lin1_W,
    const float* __restrict__ lin1_b,
    const float* __restrict__ lin2_W,
    const float* __restrict__ lin2_b,
    const float* __restrict__ last_W,
    const float* __restrict__ last_b,
    float* __restrict__ out)
{
    __shared__ SMemU sm;

    const int tid = threadIdx.x;
    const int lane = tid & 63;
    const int wv = tid >> 6;
    const int q = wv & 1;        // row-half (16 rows)
    const int t16 = wv >> 1;     // col-tile (16 cols)
    const int row0 = blockIdx.x * M;

    if (tid < 64) {    // zero K-pad: kstep 19, lanes 32..63, both rowtiles
        half8 z = {0, 0, 0, 0, 0, 0, 0, 0};
        const int qq = tid >> 5;
        *reinterpret_cast<half8*>(
            &sm.g.At[qq][((KST - 1) * 64 + 32 + (tid & 31)) * 8]) = z;
    }

    // ---- stage A-fragments from Aemb (coalesced, scale pre-applied) ----
    f32x4 v[GITER];
    int   slot[GITER];
    bool  ok[GITER];
#pragma unroll
    for (int it = 0; it < GITER; ++it) {
        const int i = tid + it * 512;
        ok[it] = (i < M * Fn * 4);
        if (ok[it]) {
            const int j = i >> 2, c = i & 3;
            const int r = j & 31, f = j >> 5;
            v[it] = *reinterpret_cast<const f32x4*>(
                Aemb + ((size_t)(row0 + r) * Fn + f) * En + c * 4);
            slot[it] = (r >> 4) * (KST * 512)
                     + (((f >> 1) * 64) + (f & 1) * 32 + (r & 15)) * 8
                     + (c >> 1) * 128 + (c & 1) * 4;
        }
    }
#pragma unroll
    for (int it = 0; it < GITER; ++it) {
        if (ok[it])
            *reinterpret_cast<half4*>(&sm.g.At[0][0] + slot[it]) = cvt4(v[it]);
    }
    __syncthreads();

    // ---- K-loop: A from LDS, B converted in-register from fp32 weights ----
    const int n = t16 * 16 + (lane & 15);          // 0..63 weight row
    const int kq = lane >> 4;                      // 0..3
    const float* wrow = (n < 32) ? (w_first + (size_t)n * 624)
                                 : (w_inner + (size_t)(n - 32) * 624);
    const _Float16* aLds = &sm.g.At[q][lane * 8];

    floatx4 acc = {0.0f, 0.0f, 0.0f, 0.0f};
#pragma unroll
    for (int t = 0; t < KST; ++t) {
        const half8 af = *reinterpret_cast<const half8*>(aLds + t * 512);
        half8 bf;
        if (t == KST - 1 && kq >= 2) {   // kb >= 624: K pad
            bf = half8{0, 0, 0, 0, 0, 0, 0, 0};
        } else {
            const int kb = t * 32 + kq * 8;
            const float4 a = *reinterpret_cast<const float4*>(wrow + kb);
            const float4 b = *reinterpret_cast<const float4*>(wrow + kb + 4);
            bf = cvt8(a, b);
        }
        acc = __builtin_amdgcn_mfma_f32_16x16x32_f16(af, bf, acc, 0, 0, 0);
    }

    __syncthreads();   // all waves done reading At -> MLP scratch may alias

    // ---- write C tile: col=lane&15, row=(lane>>4)*4+reg ----
    {
        const int col = t16 * 16 + (lane & 15);
        const int rbase = q * 16 + (lane >> 4) * 4;
#pragma unroll
        for (int r = 0; r < 4; ++r)
            sm.m.x[(rbase + r) * 69 + col] = acc[r];
    }

    // ---- stage MLP weights ----
    for (int i = tid; i < 2145; i += 512) {
        float vv;
        if (i < 1024)      vv = lin1_W[i];
        else if (i < 2048) vv = lin2_W[i - 1024];
        else if (i < 2080) vv = lin1_b[i - 2048];
        else if (i < 2112) vv = lin2_b[i - 2080];
        else if (i < 2144) vv = last_W[i - 2112];
        else               vv = last_b[0];
        sm.m.wsh[i] = vv;
    }
    __syncthreads();

    // ---- xin[j][r] = first + s^2 ----
    for (int p = tid; p < 1024; p += 512) {
        const int j = p >> 5, r = p & 31;
        const float fi = sm.m.x[r * 69 + j];
        const float sq = sm.m.x[r * 69 + 32 + j];
        sm.m.r1[j * 32 + r] = fi + sq * sq;
    }
    __syncthreads();

    // ---- layer 1 ----
    {
        const int r = tid & 31, n0 = (tid >> 5) * 2;
        float a0 = sm.m.wsh[2048 + n0];
        float a1 = sm.m.wsh[2048 + n0 + 1];
#pragma unroll
        for (int j = 0; j < 32; ++j) {
            const float xj = sm.m.r1[j * 32 + r];
            a0 = fmaf(sm.m.wsh[n0 * 32 + j],       xj, a0);
            a1 = fmaf(sm.m.wsh[(n0 + 1) * 32 + j], xj, a1);
        }
        sm.m.r2[n0 * 32 + r]       = fmaxf(a0, 0.0f);
        sm.m.r2[(n0 + 1) * 32 + r] = fmaxf(a1, 0.0f);
    }
    __syncthreads();

    // ---- layer 2 ----
    {
        const int r = tid & 31, n0 = (tid >> 5) * 2;
        float a0 = sm.m.wsh[2080 + n0];
        float a1 = sm.m.wsh[2080 + n0 + 1];
#pragma unroll
        for (int j = 0; j < 32; ++j) {
            const float xj = sm.m.r2[j * 32 + r];
            a0 = fmaf(sm.m.wsh[1024 + n0 * 32 + j],       xj, a0);
            a1 = fmaf(sm.m.wsh[1024 + (n0 + 1) * 32 + j], xj, a1);
        }
        sm.m.r1[n0 * 32 + r]       = fmaxf(a0, 0.0f);
        sm.m.r1[(n0 + 1) * 32 + r] = fmaxf(a1, 0.0f);
    }
    __syncthreads();

    // ---- last layer + store ----
    if (tid < M) {
        float res = sm.m.wsh[2144];
#pragma unroll
        for (int j = 0; j < 32; ++j)
            res = fmaf(sm.m.wsh[2112 + j], sm.m.r1[j * 32 + tid], res);
        out[row0 + tid] = res;
    }
}

} // namespace

extern "C" void kernel_launch(void* const* d_in, const int* in_sizes, int n_in,
                              void* d_out, int out_size, void* d_ws, size_t ws_size,
                              hipStream_t stream) {
    (void)in_sizes; (void)n_in; (void)out_size; (void)ws_size;
    const int*   Xi      = (const int*)d_in[0];
    const float* Xv      = (const float*)d_in[1];
    const float* T       = (const float*)d_in[2];
    const float* w_first = (const float*)d_in[3];
    const float* w_inner = (const float*)d_in[4];
    const float* lin1_W  = (const float*)d_in[5];
    const float* lin1_b  = (const float*)d_in[6];
    const float* lin2_W  = (const float*)d_in[7];
    const float* lin2_b  = (const float*)d_in[8];
    const float* last_W  = (const float*)d_in[9];
    const float* last_b  = (const float*)d_in[10];
    float* out = (float*)d_out;

    unsigned int* cur = (unsigned int*)((char*)d_ws + OFF_CUR);
    uint2*        ent = (uint2*)((char*)d_ws + OFF_ENT);
    float*        Aemb = (float*)((char*)d_ws + OFF_AEMB);

    hipLaunchKernelGGL(pnn_zero, dim3((NBUCKET + 255) / 256), dim3(256), 0, stream,
                       cur);
    hipLaunchKernelGGL(pnn_bin, dim3((NTOT + 255) / 256), dim3(256), 0, stream,
                       Xi, Xv, cur, ent);
    hipLaunchKernelGGL(pnn_select, dim3(NBUCKET), dim3(512), 0, stream,
                       T, cur, ent, Aemb);
    hipLaunchKernelGGL(pnn_gemm, dim3(Bn / M), dim3(512), 0, stream,
                       Aemb, w_first, w_inner,
                       lin1_W, lin1_b, lin2_W, lin2_b, last_W, last_b, out);
}

// Round 5
// 374.039 us; speedup vs baseline: 1.1247x; 1.1247x over previous
//
#include <hip/hip_runtime.h>

// PNN round 10: L3 (Infinity Cache) pre-warm + round-6 fused kernel.
//
// Evidence chain:
//   r6: removing 42 MB of dense traffic changed dur by 1.6 us -> gather is
//       latency-bound at ~250 GB/s effective; BW idle. Kernel < 147 us
//       (absent from top-5 which starts at 147).
//   r8: windowed-random reads + RANDOM 64B writes: +67 us.
//   r9: dense streamed reads + RANDOM 64B writes: +102 us.
//   => any random 64B HBM access (read OR write) runs at the DRAM
//      row-activate wall (~tRC-limited, ~250 GB/s). Reordering only moved
//      the scatter to the write side. r6's shape (sequential writes, random
//      reads) is right; its gather sits at the DRAM random-row wall.
//
// The only resource that bypasses the row wall: 256 MB memory-side L3.
// Table = 249.6 MB -- it FITS. The harness's ~1 GB poison fill evicts it
// every iteration, so the gather always pays DRAM prices. Fix: re-warm L3
// with one dense stream (250 MB ~= 40 us at measured 6.7 TB/s fill rate),
// then run the verified r6 fused kernel whose random reads now hit L3
// (no row-activate penalty). Nontemporal hint on gather loads REMOVED
// (we now want allocation).
//
// Prediction: chain ~145 -> ~70-100 us; dur 318 -> ~245-275.
// Falsifier: dur ~= 355 (warm added, gather unchanged) => L3 doesn't
// retain/serve as modeled => DRAM random wall is the roofline; revert to r6.

namespace {

typedef _Float16 half8 __attribute__((ext_vector_type(8)));
typedef _Float16 half4 __attribute__((ext_vector_type(4)));
typedef float floatx4 __attribute__((ext_vector_type(4)));
typedef float f32x4 __attribute__((ext_vector_type(4)));

constexpr int Bn = 16384;
constexpr int Fn = 39;
constexpr int Vn = 100000;
constexpr int En = 16;
constexpr int M = 32;                 // rows per block
constexpr int KST = 20;               // k-steps of 32 (624 padded to 640)
constexpr int GITER = 10;             // ceil(4992 / 512) gather chunk-iters

constexpr size_t T_F4 = (size_t)Fn * Vn * En / 4;   // 15,600,000 float4s
constexpr int WARM_BLOCKS = 2048;
constexpr int WARM_THREADS = 256;
constexpr size_t WARM_STRIDE = (size_t)WARM_BLOCKS * WARM_THREADS;

__device__ __forceinline__ half8 cvt8(float4 a, float4 b) {
    half8 h;
    h[0] = (_Float16)a.x; h[1] = (_Float16)a.y;
    h[2] = (_Float16)a.z; h[3] = (_Float16)a.w;
    h[4] = (_Float16)b.x; h[5] = (_Float16)b.y;
    h[6] = (_Float16)b.z; h[7] = (_Float16)b.w;
    return h;
}

__device__ __forceinline__ half4 cvt4s(f32x4 a, float s) {
    half4 h;
    h[0] = (_Float16)(a[0] * s);
    h[1] = (_Float16)(a[1] * s);
    h[2] = (_Float16)(a[2] * s);
    h[3] = (_Float16)(a[3] * s);
    return h;
}

// ---------------- K0: warm the table into L3 (dense stream) ----------------
__global__ __launch_bounds__(256) void pnn_warm(
    const float* __restrict__ T,
    float* __restrict__ scratch)
{
    const size_t gid = (size_t)blockIdx.x * WARM_THREADS + threadIdx.x;
    const f32x4* __restrict__ T4 = reinterpret_cast<const f32x4*>(T);
    float s = 0.0f;
    for (size_t i = gid; i < T_F4; i += WARM_STRIDE) {
        const f32x4 v = T4[i];
        s += v[0] + v[1] + v[2] + v[3];
    }
    // keep loads alive; 2 MB coalesced write, never read back
    scratch[gid] = s;
}

// ---------------- K1: round-6 fused kernel (verified) ----------------
struct SMemGather {
    _Float16 At[2][KST * 512];   // 2 rowtiles x 10240 halfs = 40 KB
    int   xi[M * Fn];            // 1248
    float xv[M * Fn];            // 1248
};

struct SMemMlp {
    float x[M * 69];     // x[row][d], stride 69 -> conflict-free
    float wsh[2176];     // lin1_W[0..1023] lin2_W[1024..2047] b1@2048 b2@2080 lastW@2112 lastb@2144
    float r1[1024];
    float r2[1024];
};

union SMemU {
    SMemGather g;        // live: stage + gather + K-loop
    SMemMlp m;           // live: after post-K barrier
};

__global__ __launch_bounds__(512, 4) void pnn_fused(
    const int* __restrict__ Xi,
    const float* __restrict__ Xv,
    const float* __restrict__ T,
    const float* __restrict__ w_first,
    const float* __restrict__ w_inner,
    const float* __restrict__ lin1_W,
    const float* __restrict__ lin1_b,
    const float* __restrict__ lin2_W,
    const float* __restrict__ lin2_b,
    const float* __restrict__ last_W,
    const float* __restrict__ last_b,
    float* __restrict__ out)
{
    __shared__ SMemU sm;

    const int tid = threadIdx.x;
    const int lane = tid & 63;
    const int wv = tid >> 6;
    const int q = wv & 1;        // row-half (16 rows)
    const int t16 = wv >> 1;     // col-tile (16 cols)
    const int row0 = blockIdx.x * M;

    // ---- stage Xi/Xv coalesced (1248 ints/floats = 312 x 16B each) ----
    if (tid < 312) {
        reinterpret_cast<int4*>(sm.g.xi)[tid] =
            reinterpret_cast<const int4*>(Xi + (size_t)row0 * Fn)[tid];
        reinterpret_cast<float4*>(sm.g.xv)[tid] =
            reinterpret_cast<const float4*>(Xv + (size_t)row0 * Fn)[tid];
    }
    if (tid < 64) {    // zero K-pad: kstep 19, lanes 32..63, both rowtiles
        half8 z = {0, 0, 0, 0, 0, 0, 0, 0};
        const int qq = tid >> 5;
        *reinterpret_cast<half8*>(
            &sm.g.At[qq][((KST - 1) * 64 + 32 + (tid & 31)) * 8]) = z;
    }
    __syncthreads();

    // ---- gather: task i (0..4991): line j=i>>2 (row r=j&31, feat f=j>>5),
    // chunk c=i&3. 4 consecutive lanes share one 64B line. All loads issued
    // before any LDS write. PLAIN loads (we want L3 hits from the warm). ----
    f32x4 v[GITER];
    float s[GITER];
    int   slot[GITER];
    bool  ok[GITER];
#pragma unroll
    for (int it = 0; it < GITER; ++it) {
        const int i = tid + it * 512;
        ok[it] = (i < M * Fn * 4);
        if (ok[it]) {
            const int j = i >> 2, c = i & 3;
            const int r = j & 31, f = j >> 5;
            const int idx = sm.g.xi[r * Fn + f];
            s[it] = sm.g.xv[r * Fn + f];
            v[it] = *reinterpret_cast<const f32x4*>(
                T + ((size_t)f * Vn + (size_t)idx) * En + c * 4);
            slot[it] = (r >> 4) * (KST * 512)
                     + (((f >> 1) * 64) + (f & 1) * 32 + (r & 15)) * 8
                     + (c >> 1) * 128 + (c & 1) * 4;
        }
    }
#pragma unroll
    for (int it = 0; it < GITER; ++it) {
        if (ok[it])
            *reinterpret_cast<half4*>(&sm.g.At[0][0] + slot[it]) =
                cvt4s(v[it], s[it]);
    }
    __syncthreads();

    // ---- K-loop: A from LDS, B converted in-register from fp32 weights ----
    const int n = t16 * 16 + (lane & 15);          // 0..63 weight row
    const int kq = lane >> 4;                      // 0..3
    const float* wrow = (n < 32) ? (w_first + (size_t)n * 624)
                                 : (w_inner + (size_t)(n - 32) * 624);
    const _Float16* aLds = &sm.g.At[q][lane * 8];

    floatx4 acc = {0.0f, 0.0f, 0.0f, 0.0f};
#pragma unroll
    for (int t = 0; t < KST; ++t) {
        const half8 af = *reinterpret_cast<const half8*>(aLds + t * 512);
        half8 bf;
        if (t == KST - 1 && kq >= 2) {   // kb >= 624: K pad
            bf = half8{0, 0, 0, 0, 0, 0, 0, 0};
        } else {
            const int kb = t * 32 + kq * 8;
            const float4 a = *reinterpret_cast<const float4*>(wrow + kb);
            const float4 b = *reinterpret_cast<const float4*>(wrow + kb + 4);
            bf = cvt8(a, b);
        }
        acc = __builtin_amdgcn_mfma_f32_16x16x32_f16(af, bf, acc, 0, 0, 0);
    }

    __syncthreads();   // all waves done reading At -> MLP scratch may alias

    // ---- write C tile: col=lane&15, row=(lane>>4)*4+reg ----
    {
        const int col = t16 * 16 + (lane & 15);
        const int rbase = q * 16 + (lane >> 4) * 4;
#pragma unroll
        for (int r = 0; r < 4; ++r)
            sm.m.x[(rbase + r) * 69 + col] = acc[r];
    }

    // ---- stage MLP weights ----
    for (int i = tid; i < 2145; i += 512) {
        float vv;
        if (i < 1024)      vv = lin1_W[i];
        else if (i < 2048) vv = lin2_W[i - 1024];
        else if (i < 2080) vv = lin1_b[i - 2048];
        else if (i < 2112) vv = lin2_b[i - 2080];
        else if (i < 2144) vv = last_W[i - 2112];
        else               vv = last_b[0];
        sm.m.wsh[i] = vv;
    }
    __syncthreads();

    // ---- xin[j][r] = first + s^2 ----
    for (int p = tid; p < 1024; p += 512) {
        const int j = p >> 5, r = p & 31;
        const float fi = sm.m.x[r * 69 + j];
        const float sq = sm.m.x[r * 69 + 32 + j];
        sm.m.r1[j * 32 + r] = fi + sq * sq;
    }
    __syncthreads();

    // ---- layer 1 ----
    {
        const int r = tid & 31, n0 = (tid >> 5) * 2;
        float a0 = sm.m.wsh[2048 + n0];
        float a1 = sm.m.wsh[2048 + n0 + 1];
#pragma unroll
        for (int j = 0; j < 32; ++j) {
            const float xj = sm.m.r1[j * 32 + r];
            a0 = fmaf(sm.m.wsh[n0 * 32 + j],       xj, a0);
            a1 = fmaf(sm.m.wsh[(n0 + 1) * 32 + j], xj, a1);
        }
        sm.m.r2[n0 * 32 + r]       = fmaxf(a0, 0.0f);
        sm.m.r2[(n0 + 1) * 32 + r] = fmaxf(a1, 0.0f);
    }
    __syncthreads();

    // ---- layer 2 ----
    {
        const int r = tid & 31, n0 = (tid >> 5) * 2;
        float a0 = sm.m.wsh[2080 + n0];
        float a1 = sm.m.wsh[2080 + n0 + 1];
#pragma unroll
        for (int j = 0; j < 32; ++j) {
            const float xj = sm.m.r2[j * 32 + r];
            a0 = fmaf(sm.m.wsh[1024 + n0 * 32 + j],       xj, a0);
            a1 = fmaf(sm.m.wsh[1024 + (n0 + 1) * 32 + j], xj, a1);
        }
        sm.m.r1[n0 * 32 + r]       = fmaxf(a0, 0.0f);
        sm.m.r1[(n0 + 1) * 32 + r] = fmaxf(a1, 0.0f);
    }
    __syncthreads();

    // ---- last layer + store ----
    if (tid < M) {
        float res = sm.m.wsh[2144];
#pragma unroll
        for (int j = 0; j < 32; ++j)
            res = fmaf(sm.m.wsh[2112 + j], sm.m.r1[j * 32 + tid], res);
        out[row0 + tid] = res;
    }
}

} // namespace

extern "C" void kernel_launch(void* const* d_in, const int* in_sizes, int n_in,
                              void* d_out, int out_size, void* d_ws, size_t ws_size,
                              hipStream_t stream) {
    (void)in_sizes; (void)n_in; (void)out_size; (void)ws_size;
    const int*   Xi      = (const int*)d_in[0];
    const float* Xv      = (const float*)d_in[1];
    const float* T       = (const float*)d_in[2];
    const float* w_first = (const float*)d_in[3];
    const float* w_inner = (const float*)d_in[4];
    const float* lin1_W  = (const float*)d_in[5];
    const float* lin1_b  = (const float*)d_in[6];
    const float* lin2_W  = (const float*)d_in[7];
    const float* lin2_b  = (const float*)d_in[8];
    const float* last_W  = (const float*)d_in[9];
    const float* last_b  = (const float*)d_in[10];
    float* out = (float*)d_out;
    float* scratch = (float*)d_ws;

    hipLaunchKernelGGL(pnn_warm, dim3(WARM_BLOCKS), dim3(WARM_THREADS), 0, stream,
                       T, scratch);
    hipLaunchKernelGGL(pnn_fused, dim3(Bn / M), dim3(512), 0, stream,
                       Xi, Xv, T, w_first, w_inner,
                       lin1_W, lin1_b, lin2_W, lin2_b, last_W, last_b, out);
}

// Round 6
// 319.840 us; speedup vs baseline: 1.3153x; 1.1695x over previous
//
#include <hip/hip_runtime.h>

// PNN round 11: REVERT to round-6 fused kernel (best verified: 318.4 us).
//
// Session evidence (5 experiments):
//   r6  (this kernel): 318.4 us -- full fusion; removing 42 MB of dense
//       traffic + a launch vs r5 changed dur by only 1.6 us -> gather is
//       latency-bound, BW idle during gather.
//   r8  bin+windowed-random reads:  385.7 us (+67)  -> locality no help;
//       random 64 B writes hit the same wall as random reads.
//   r9  bin+dense-stream+random writes: 420.7 us (+102) -> confirms write wall.
//   r10 L3 pre-warm + r6: 374.0 us (= 318 + warm cost, gather unchanged)
//       -> the 249.6 MB table cannot be made L3-resident (table ~= whole
//       256 MB MALL; streaming warm self-evicts; poison fill wipes it).
//
// Conclusion: the 639K x 64 B random gather sits at the hardware
// random-access wall; every (b,f) needs exactly one table line (dedup
// potential ~8%); the timed window also contains ~149 us of harness poison
// fill at 84% of HBM peak + input restores. All three terms are immovable
// from kernel source. This revert re-establishes the floor.

namespace {

typedef _Float16 half8 __attribute__((ext_vector_type(8)));
typedef _Float16 half4 __attribute__((ext_vector_type(4)));
typedef float floatx4 __attribute__((ext_vector_type(4)));
typedef float f32x4 __attribute__((ext_vector_type(4)));

constexpr int Bn = 16384;
constexpr int Fn = 39;
constexpr int Vn = 100000;
constexpr int En = 16;
constexpr int M = 32;                 // rows per block
constexpr int KST = 20;               // k-steps of 32 (624 padded to 640)
constexpr int GITER = 10;             // ceil(4992 / 512) gather chunk-iters

__device__ __forceinline__ half8 cvt8(float4 a, float4 b) {
    half8 h;
    h[0] = (_Float16)a.x; h[1] = (_Float16)a.y;
    h[2] = (_Float16)a.z; h[3] = (_Float16)a.w;
    h[4] = (_Float16)b.x; h[5] = (_Float16)b.y;
    h[6] = (_Float16)b.z; h[7] = (_Float16)b.w;
    return h;
}

__device__ __forceinline__ half4 cvt4s(f32x4 a, float s) {
    half4 h;
    h[0] = (_Float16)(a[0] * s);
    h[1] = (_Float16)(a[1] * s);
    h[2] = (_Float16)(a[2] * s);
    h[3] = (_Float16)(a[3] * s);
    return h;
}

struct SMemGather {
    _Float16 At[2][KST * 512];   // 2 rowtiles x 10240 halfs = 40 KB
    int   xi[M * Fn];            // 1248
    float xv[M * Fn];            // 1248
};

struct SMemMlp {
    float x[M * 69];     // x[row][d], stride 69 -> conflict-free
    float wsh[2176];     // lin1_W[0..1023] lin2_W[1024..2047] b1@2048 b2@2080 lastW@2112 lastb@2144
    float r1[1024];
    float r2[1024];
};

union SMemU {
    SMemGather g;        // 50,944 B (live: stage + gather + K-loop)
    SMemMlp m;           // 25,728 B (live: after post-K barrier)
};

__global__ __launch_bounds__(512, 4) void pnn_fused(
    const int* __restrict__ Xi,
    const float* __restrict__ Xv,
    const float* __restrict__ T,
    const float* __restrict__ w_first,
    const float* __restrict__ w_inner,
    const float* __restrict__ lin1_W,
    const float* __restrict__ lin1_b,
    const float* __restrict__ lin2_W,
    const float* __restrict__ lin2_b,
    const float* __restrict__ last_W,
    const float* __restrict__ last_b,
    float* __restrict__ out)
{
    __shared__ SMemU sm;

    const int tid = threadIdx.x;
    const int lane = tid & 63;
    const int wv = tid >> 6;
    const int q = wv & 1;        // row-half (16 rows)
    const int t16 = wv >> 1;     // col-tile (16 cols)
    const int row0 = blockIdx.x * M;

    // ---- stage Xi/Xv coalesced (1248 ints/floats = 312 x 16B each) ----
    if (tid < 312) {
        reinterpret_cast<int4*>(sm.g.xi)[tid] =
            reinterpret_cast<const int4*>(Xi + (size_t)row0 * Fn)[tid];
        reinterpret_cast<float4*>(sm.g.xv)[tid] =
            reinterpret_cast<const float4*>(Xv + (size_t)row0 * Fn)[tid];
    }
    if (tid < 64) {    // zero K-pad: kstep 19, lanes 32..63, both rowtiles
        half8 z = {0, 0, 0, 0, 0, 0, 0, 0};
        const int qq = tid >> 5;
        *reinterpret_cast<half8*>(
            &sm.g.At[qq][((KST - 1) * 64 + 32 + (tid & 31)) * 8]) = z;
    }
    __syncthreads();

    // ---- gather: task i (0..4991): line j=i>>2 (row r=j&31, feat f=j>>5),
    // chunk c=i&3. 4 consecutive lanes share one 64B line -> wave instr
    // touches 16 lines, 4-lane coalesced. All loads issued before any LDS
    // write (batched latency). Nontemporal: reuse ~1.08, don't pollute L2.
    f32x4 v[GITER];
    float s[GITER];
    int   slot[GITER];
    bool  ok[GITER];
#pragma unroll
    for (int it = 0; it < GITER; ++it) {
        const int i = tid + it * 512;
        ok[it] = (i < M * Fn * 4);
        if (ok[it]) {
            const int j = i >> 2, c = i & 3;
            const int r = j & 31, f = j >> 5;
            const int idx = sm.g.xi[r * Fn + f];
            s[it] = sm.g.xv[r * Fn + f];
            const f32x4* src = reinterpret_cast<const f32x4*>(
                T + ((size_t)f * Vn + (size_t)idx) * En + c * 4);
            v[it] = __builtin_nontemporal_load(src);
            // A-frag slot (halfs), verified layout, rowtile = r>>4:
            slot[it] = (r >> 4) * (KST * 512)
                     + (((f >> 1) * 64) + (f & 1) * 32 + (r & 15)) * 8
                     + (c >> 1) * 128 + (c & 1) * 4;
        }
    }
#pragma unroll
    for (int it = 0; it < GITER; ++it) {
        if (ok[it])
            *reinterpret_cast<half4*>(&sm.g.At[0][0] + slot[it]) =
                cvt4s(v[it], s[it]);
    }
    __syncthreads();

    // ---- K-loop: A from LDS, B converted in-register from fp32 weights ----
    // lane holds B[col = t16*16 + (lane&15)][k = kq*8 .. kq*8+7] per step.
    const int n = t16 * 16 + (lane & 15);          // 0..63 weight row
    const int kq = lane >> 4;                      // 0..3
    const float* wrow = (n < 32) ? (w_first + (size_t)n * 624)
                                 : (w_inner + (size_t)(n - 32) * 624);
    const _Float16* aLds = &sm.g.At[q][lane * 8];

    floatx4 acc = {0.0f, 0.0f, 0.0f, 0.0f};
#pragma unroll
    for (int t = 0; t < KST; ++t) {
        const half8 af = *reinterpret_cast<const half8*>(aLds + t * 512);
        half8 bf;
        if (t == KST - 1 && kq >= 2) {   // kb >= 624: K pad, avoid OOB/NaN
            bf = half8{0, 0, 0, 0, 0, 0, 0, 0};
        } else {
            const int kb = t * 32 + kq * 8;
            const float4 a = *reinterpret_cast<const float4*>(wrow + kb);
            const float4 b = *reinterpret_cast<const float4*>(wrow + kb + 4);
            bf = cvt8(a, b);
        }
        acc = __builtin_amdgcn_mfma_f32_16x16x32_f16(af, bf, acc, 0, 0, 0);
    }

    // all waves done reading At -> MLP scratch may alias it
    __syncthreads();

    // ---- write C tile: col=lane&15, row=(lane>>4)*4+reg ----
    {
        const int col = t16 * 16 + (lane & 15);
        const int rbase = q * 16 + (lane >> 4) * 4;
#pragma unroll
        for (int r = 0; r < 4; ++r)
            sm.m.x[(rbase + r) * 69 + col] = acc[r];
    }

    // ---- stage MLP weights ----
    for (int i = tid; i < 2145; i += 512) {
        float vv;
        if (i < 1024)      vv = lin1_W[i];
        else if (i < 2048) vv = lin2_W[i - 1024];
        else if (i < 2080) vv = lin1_b[i - 2048];
        else if (i < 2112) vv = lin2_b[i - 2080];
        else if (i < 2144) vv = last_W[i - 2112];
        else               vv = last_b[0];
        sm.m.wsh[i] = vv;
    }
    __syncthreads();

    // ---- xin[j][r] = first + s^2 ----
    for (int p = tid; p < 1024; p += 512) {
        const int j = p >> 5, r = p & 31;
        const float fi = sm.m.x[r * 69 + j];
        const float sq = sm.m.x[r * 69 + 32 + j];
        sm.m.r1[j * 32 + r] = fi + sq * sq;
    }
    __syncthreads();

    // ---- layer 1 ----
    {
        const int r = tid & 31, n0 = (tid >> 5) * 2;
        float a0 = sm.m.wsh[2048 + n0];
        float a1 = sm.m.wsh[2048 + n0 + 1];
#pragma unroll
        for (int j = 0; j < 32; ++j) {
            const float xj = sm.m.r1[j * 32 + r];
            a0 = fmaf(sm.m.wsh[n0 * 32 + j],       xj, a0);
            a1 = fmaf(sm.m.wsh[(n0 + 1) * 32 + j], xj, a1);
        }
        sm.m.r2[n0 * 32 + r]       = fmaxf(a0, 0.0f);
        sm.m.r2[(n0 + 1) * 32 + r] = fmaxf(a1, 0.0f);
    }
    __syncthreads();

    // ---- layer 2 ----
    {
        const int r = tid & 31, n0 = (tid >> 5) * 2;
        float a0 = sm.m.wsh[2080 + n0];
        float a1 = sm.m.wsh[2080 + n0 + 1];
#pragma unroll
        for (int j = 0; j < 32; ++j) {
            const float xj = sm.m.r2[j * 32 + r];
            a0 = fmaf(sm.m.wsh[1024 + n0 * 32 + j],       xj, a0);
            a1 = fmaf(sm.m.wsh[1024 + (n0 + 1) * 32 + j], xj, a1);
        }
        sm.m.r1[n0 * 32 + r]       = fmaxf(a0, 0.0f);
        sm.m.r1[(n0 + 1) * 32 + r] = fmaxf(a1, 0.0f);
    }
    __syncthreads();

    // ---- last layer + store ----
    if (tid < M) {
        float res = sm.m.wsh[2144];
#pragma unroll
        for (int j = 0; j < 32; ++j)
            res = fmaf(sm.m.wsh[2112 + j], sm.m.r1[j * 32 + tid], res);
        out[row0 + tid] = res;
    }
}

} // namespace

extern "C" void kernel_launch(void* const* d_in, const int* in_sizes, int n_in,
                              void* d_out, int out_size, void* d_ws, size_t ws_size,
                              hipStream_t stream) {
    (void)in_sizes; (void)n_in; (void)out_size; (void)d_ws; (void)ws_size;
    const int*   Xi      = (const int*)d_in[0];
    const float* Xv      = (const float*)d_in[1];
    const float* T       = (const float*)d_in[2];
    const float* w_first = (const float*)d_in[3];
    const float* w_inner = (const float*)d_in[4];
    const float* lin1_W  = (const float*)d_in[5];
    const float* lin1_b  = (const float*)d_in[6];
    const float* lin2_W  = (const float*)d_in[7];
    const float* lin2_b  = (const float*)d_in[8];
    const float* last_W  = (const float*)d_in[9];
    const float* last_b  = (const float*)d_in[10];
    float* out = (float*)d_out;

    hipLaunchKernelGGL(pnn_fused, dim3(Bn / M), dim3(512), 0, stream,
                       Xi, Xv, T, w_first, w_inner,
                       lin1_W, lin1_b, lin2_W, lin2_b, last_W, last_b, out);
}